// Round 10
// baseline (353.055 us; speedup 1.0000x reference)
//
#include <hip/hip_runtime.h>

#define N_NODES 100000
#define N_EDGES 1600000
#define NUM_GRAPHS 128

#define BSH 10
#define NBUCK 98                  // ceil(N_NODES / 1024)
#define NBLKP 500                 // partition blocks
#define EPB (N_EDGES / NBLKP)     // 3200
#define SOFF (NBUCK * NBLKP)      // 49000
#define NSCAN (2 * NBUCK * NBLKP) // 98000
#define SCAN_BS 1024
#define NBSC ((NSCAN + SCAN_BS - 1) / SCAN_BS)  // 96

__device__ __forceinline__ unsigned bf16pair(float a, float b) {
    unsigned ua = __float_as_uint(a), ub = __float_as_uint(b);
    ua = (ua + 0x7FFFu + ((ua >> 16) & 1u)) >> 16;
    ub = (ub + 0x7FFFu + ((ub >> 16) & 1u)) >> 16;
    return ua | (ub << 16);
}
__device__ __forceinline__ float bflo(unsigned u) { return __uint_as_float(u << 16); }
__device__ __forceinline__ float bfhi(unsigned u) { return __uint_as_float(u & 0xFFFF0000u); }

// ---------------- Phase A: per-block coarse histograms (dst & src), wave-private sub-hists ----------------
__global__ __launch_bounds__(256) void part_hist(const int* __restrict__ src,
                                                 const int* __restrict__ dst,
                                                 int* __restrict__ cnt) {
    __shared__ int hd[4 * NBUCK], hs[4 * NBUCK];
    int t = threadIdx.x;
    for (int i = t; i < 4 * NBUCK; i += 256) { hd[i] = 0; hs[i] = 0; }
    __syncthreads();
    int wid = t >> 6;
    int* hdw = hd + wid * NBUCK;
    int* hsw = hs + wid * NBUCK;
    int e0 = blockIdx.x * EPB;
    for (int j = 4 * t; j + 3 < EPB; j += 1024) {
        int4 s4 = *(const int4*)(src + e0 + j);
        int4 d4 = *(const int4*)(dst + e0 + j);
        atomicAdd(&hdw[d4.x >> BSH], 1); atomicAdd(&hdw[d4.y >> BSH], 1);
        atomicAdd(&hdw[d4.z >> BSH], 1); atomicAdd(&hdw[d4.w >> BSH], 1);
        atomicAdd(&hsw[s4.x >> BSH], 1); atomicAdd(&hsw[s4.y >> BSH], 1);
        atomicAdd(&hsw[s4.z >> BSH], 1); atomicAdd(&hsw[s4.w >> BSH], 1);
    }
    __syncthreads();
    int bk = blockIdx.x;
    for (int i = t; i < NBUCK; i += 256) {
        cnt[i * NBLKP + bk] = hd[i] + hd[NBUCK + i] + hd[2 * NBUCK + i] + hd[3 * NBUCK + i];
        cnt[SOFF + i * NBLKP + bk] = hs[i] + hs[NBUCK + i] + hs[2 * NBUCK + i] + hs[3 * NBUCK + i];
    }
}

// ---------------- exclusive scan ----------------
__global__ __launch_bounds__(256) void scan1(const int* __restrict__ cnt, int* __restrict__ excl,
                                             int* __restrict__ blksum, int n) {
    __shared__ int tmp[256];
    int t = threadIdx.x;
    int idx0 = blockIdx.x * SCAN_BS + t * 4;
    int v[4];
#pragma unroll
    for (int k = 0; k < 4; ++k) { int i = idx0 + k; v[k] = (i < n) ? cnt[i] : 0; }
    int sum = v[0] + v[1] + v[2] + v[3];
    tmp[t] = sum;
    __syncthreads();
    for (int off = 1; off < 256; off <<= 1) {
        int y = (t >= off) ? tmp[t - off] : 0;
        __syncthreads();
        tmp[t] += y;
        __syncthreads();
    }
    int run = (t > 0) ? tmp[t - 1] : 0;
#pragma unroll
    for (int k = 0; k < 4; ++k) { int i = idx0 + k; if (i < n) excl[i] = run; run += v[k]; }
    if (t == 255) blksum[blockIdx.x] = tmp[255];
}

__global__ __launch_bounds__(256) void scan2(int* __restrict__ blksum, int nb) {
    __shared__ int tmp[256];
    int t = threadIdx.x;
    int C = (nb + 255) / 256;
    int base = t * C;
    int s = 0;
    for (int k = 0; k < C; ++k) { int i = base + k; if (i < nb) s += blksum[i]; }
    tmp[t] = s;
    __syncthreads();
    for (int off = 1; off < 256; off <<= 1) {
        int y = (t >= off) ? tmp[t - off] : 0;
        __syncthreads();
        tmp[t] += y;
        __syncthreads();
    }
    int run = (t > 0) ? tmp[t - 1] : 0;
    for (int k = 0; k < C; ++k) {
        int i = base + k;
        if (i < nb) { int v = blksum[i]; blksum[i] = run; run += v; }
    }
}

// ---------------- Phase C: partition edges into coarse buckets (LDS cursors) ----------------
__global__ __launch_bounds__(256) void part_scatter(const int* __restrict__ src,
                                                    const int* __restrict__ dst,
                                                    const int* __restrict__ cnt,
                                                    const int* __restrict__ blk,
                                                    unsigned* __restrict__ pdst,
                                                    unsigned short* __restrict__ psrc) {
    __shared__ int cd[NBUCK], cs[NBUCK];
    int bk = blockIdx.x;
    int t = threadIdx.x;
    for (int i = t; i < NBUCK; i += 256) {
        int ii = i * NBLKP + bk;
        cd[i] = cnt[ii] + blk[ii >> 10];
        int jj = SOFF + i * NBLKP + bk;
        cs[i] = cnt[jj] + blk[jj >> 10] - N_EDGES;
    }
    __syncthreads();
    int e0 = bk * EPB;
    for (int j = 4 * t; j + 3 < EPB; j += 1024) {
        int4 s4 = *(const int4*)(src + e0 + j);
        int4 d4 = *(const int4*)(dst + e0 + j);
        int ss[4] = { s4.x, s4.y, s4.z, s4.w };
        int dd[4] = { d4.x, d4.y, d4.z, d4.w };
#pragma unroll
        for (int u = 0; u < 4; ++u) {
            int s = ss[u], d = dd[u];
            int pd = atomicAdd(&cd[d >> BSH], 1);
            pdst[pd] = (unsigned)s | ((unsigned)(d & 1023) << 17);
            int ps = atomicAdd(&cs[s >> BSH], 1);
            psrc[ps] = (unsigned short)(s & 1023);
        }
    }
}

// ---------------- Phase D (merged): blocks 0..NBUCK-1 build CSR; blocks NBUCK.. src degrees ----------------
__global__ __launch_bounds__(1024) void phase_d(const unsigned* __restrict__ pdst,
                                                const unsigned short* __restrict__ psrc,
                                                const int* __restrict__ cnt,
                                                const int* __restrict__ blk,
                                                int* __restrict__ ecol, int* __restrict__ row_start,
                                                float* __restrict__ isqi, float* __restrict__ isqo,
                                                int nN) {
    __shared__ int lh[1024];
    __shared__ int lsc[1024];
    int t = threadIdx.x;
    if (blockIdx.x < NBUCK) {
        int bu = blockIdx.x;
        int i0 = bu * NBLKP;
        int b0 = cnt[i0] + blk[i0 >> 10];
        int b1;
        if (bu == NBUCK - 1) b1 = N_EDGES;
        else { int i1 = i0 + NBLKP; b1 = cnt[i1] + blk[i1 >> 10]; }
        lh[t] = 0;
        __syncthreads();
        for (int j = b0 + t; j < b1; j += 1024)
            atomicAdd(&lh[pdst[j] >> 17], 1);
        __syncthreads();
        int myc = lh[t];
        lsc[t] = myc;
        __syncthreads();
        for (int off = 1; off < 1024; off <<= 1) {
            int y = (t >= off) ? lsc[t - off] : 0;
            __syncthreads();
            lsc[t] += y;
            __syncthreads();
        }
        int excl = lsc[t] - myc;
        int node = (bu << BSH) + t;
        if (node < nN) {
            row_start[node] = b0 + excl;
            isqi[node] = rsqrtf(fmaxf((float)myc, 1.0f));
        }
        __syncthreads();
        lh[t] = b0 + excl;   // reuse as cursor
        __syncthreads();
        for (int j = b0 + t; j < b1; j += 1024) {
            unsigned w = pdst[j];
            int pos = atomicAdd(&lh[w >> 17], 1);
            ecol[pos] = (int)(w & 0x1FFFFu);
        }
    } else {
        int bu = blockIdx.x - NBUCK;
        int i0 = SOFF + bu * NBLKP;
        int b0 = cnt[i0] + blk[i0 >> 10] - N_EDGES;
        int b1;
        if (bu == NBUCK - 1) b1 = N_EDGES;
        else { int i1 = i0 + NBLKP; b1 = cnt[i1] + blk[i1 >> 10] - N_EDGES; }
        lh[t] = 0;
        __syncthreads();
        for (int j = b0 + t; j < b1; j += 1024)
            atomicAdd(&lh[psrc[j]], 1);
        __syncthreads();
        int node = (bu << BSH) + t;
        if (node < nN) isqo[node] = rsqrtf(fmaxf((float)lh[t], 1.0f));
    }
}

// ---------------- prescale: xsu = bf16(x * isqo), contiguous 36 u32/row ----------------
__global__ void prescale_kernel(const float* __restrict__ x, const float* __restrict__ isqo,
                                unsigned* __restrict__ xsu, int nN) {
    int wave = (int)(((unsigned)blockIdx.x * blockDim.x + threadIdx.x) >> 6);
    int lane = threadIdx.x & 63;
    if (wave >= nN || lane >= 36) return;
    float s = isqo[wave];
    int c = 2 * lane;
    float a = (c < 69) ? x[(size_t)wave * 69 + c] * s : 0.0f;
    float b = (c + 1 < 69) ? x[(size_t)wave * 69 + c + 1] * s : 0.0f;
    xsu[(size_t)wave * 36 + lane] = bf16pair(a, b);
}

// ---------------- fused gather1 + GEMM1: h1[n] = bf16(relu( (isqi[n]*sum xsu[src]) @ W1 )) ----------------
// 1024 threads = 16 waves; wave per dst node. Gather: lanes 0..35 (r6 layout, 8-deep unroll).
// Matvec: all 64 lanes, 2 output cols each, W1 f32 in LDS (rows 69..71 zero).
__global__ __launch_bounds__(1024) void gather1_gemm1(const unsigned* __restrict__ xsu,
                                                      const int* __restrict__ ecol,
                                                      const int* __restrict__ row_start,
                                                      const float* __restrict__ dscale,
                                                      const float* __restrict__ W1,
                                                      unsigned* __restrict__ h1, int nN, int nE) {
    __shared__ float Wl[72 * 128];
    for (int i = threadIdx.x; i < 72 * 128; i += 1024)
        Wl[i] = (i < 69 * 128) ? W1[i] : 0.0f;
    __syncthreads();

    int wave = blockIdx.x * 16 + (threadIdx.x >> 6);
    int lane = threadIdx.x & 63;
    if (wave >= nN) return;
    int beg = row_start[wave];
    int end = (wave == nN - 1) ? nE : row_start[wave + 1];
    bool act = (lane < 36);
    float ax = 0.0f, ay = 0.0f;
    for (int j0 = beg; j0 < end; j0 += 64) {
        int ne = min(64, end - j0);
        int eidx = (lane < ne) ? ecol[j0 + lane] : 0;
        int k = 0;
        for (; k + 8 <= ne; k += 8) {
            unsigned v[8];
#pragma unroll
            for (int u = 0; u < 8; ++u) {
                int s = __shfl(eidx, k + u);
                v[u] = act ? xsu[(size_t)s * 36 + lane] : 0u;
            }
#pragma unroll
            for (int u = 0; u < 8; ++u) { ax += bflo(v[u]); ay += bfhi(v[u]); }
        }
        for (; k + 2 <= ne; k += 2) {
            int s0 = __shfl(eidx, k), s1 = __shfl(eidx, k + 1);
            unsigned v0 = act ? xsu[(size_t)s0 * 36 + lane] : 0u;
            unsigned v1 = act ? xsu[(size_t)s1 * 36 + lane] : 0u;
            ax += bflo(v0) + bflo(v1); ay += bfhi(v0) + bfhi(v1);
        }
        for (; k < ne; ++k) {
            int s = __shfl(eidx, k);
            unsigned v = act ? xsu[(size_t)s * 36 + lane] : 0u;
            ax += bflo(v); ay += bfhi(v);
        }
    }
    float dsc = dscale[wave];
    float a0 = act ? ax * dsc : 0.0f;   // col 2*lane   of agg row
    float a1 = act ? ay * dsc : 0.0f;   // col 2*lane+1 of agg row

    // matvec vs W1: lane computes output cols (2*lane, 2*lane+1)
    float acc0 = 0.0f, acc1 = 0.0f;
    int c2 = 2 * lane;
#pragma unroll 4
    for (int kk = 0; kk < 36; ++kk) {
        float v0 = __shfl(a0, kk);
        float v1 = __shfl(a1, kk);
        float2 w0 = *(const float2*)&Wl[(2 * kk) * 128 + c2];
        float2 w1 = *(const float2*)&Wl[(2 * kk + 1) * 128 + c2];
        acc0 += v0 * w0.x + v1 * w1.x;
        acc1 += v0 * w0.y + v1 * w1.y;
    }
    acc0 = fmaxf(acc0, 0.0f);
    acc1 = fmaxf(acc1, 0.0f);
    h1[(size_t)wave * 64 + lane] = bf16pair(acc0, acc1);
}

// ---------------- gather2: agg[n][0..63] f32; 2 edges/step ----------------
__global__ void gather2_kernel(const unsigned* __restrict__ feat, const int* __restrict__ ecol,
                               const int* __restrict__ row_start, const float* __restrict__ dscale,
                               float* __restrict__ agg, int nN, int nE) {
    int wave = (int)(((unsigned)blockIdx.x * blockDim.x + threadIdx.x) >> 6);
    int lane = threadIdx.x & 63;
    if (wave >= nN) return;
    int beg = row_start[wave];
    int end = (wave == nN - 1) ? nE : row_start[wave + 1];
    int half = lane >> 5;
    int c = lane & 31;
    float ax = 0.0f, ay = 0.0f;
    for (int j0 = beg; j0 < end; j0 += 64) {
        int ne = min(64, end - j0);
        int eidx = (lane < ne) ? ecol[j0 + lane] : 0;
        int k = 0;
        for (; k + 16 <= ne; k += 16) {
            unsigned v[8];
#pragma unroll
            for (int u = 0; u < 8; ++u) {
                int s = __shfl(eidx, k + 2 * u + half);
                v[u] = feat[(size_t)s * 32 + c];
            }
#pragma unroll
            for (int u = 0; u < 8; ++u) { ax += bflo(v[u]); ay += bfhi(v[u]); }
        }
        for (; k + 2 <= ne; k += 2) {
            int s = __shfl(eidx, k + half);
            unsigned v = feat[(size_t)s * 32 + c];
            ax += bflo(v); ay += bfhi(v);
        }
        if (k < ne) {
            int s = __shfl(eidx, k);
            if (half == 0) {
                unsigned v = feat[(size_t)s * 32 + c];
                ax += bflo(v); ay += bfhi(v);
            }
        }
    }
    ax += __shfl_xor(ax, 32);
    ay += __shfl_xor(ay, 32);
    if (half == 0) {
        float dsc = dscale[wave];
        ((float2*)(agg + (size_t)wave * 64))[c] = make_float2(ax * dsc, ay * dsc);
    }
}

// ---------------- register-blocked node GEMM (bf16-packed in, bf16-packed out, *rowscale) ----------------
template<int KP, int K, int NO, bool RELU, bool SCALE, bool BF16OUT, bool BF16IN>
__global__ __launch_bounds__(256) void node_gemm(const void* __restrict__ in,
                                                 const float* __restrict__ W,
                                                 const float* __restrict__ rowscale,
                                                 void* __restrict__ out, int nN) {
    constexpr int CG = NO / 8;
    constexpr int RT = 256 / CG;
    constexpr int ROWS = RT * 4;
    __shared__ float Wl[KP * NO];
    for (int i = threadIdx.x; i < KP * NO; i += 256)
        Wl[i] = (i < K * NO) ? W[i] : 0.0f;
    __syncthreads();

    int cg = threadIdx.x % CG;
    int rt = threadIdx.x / CG;
    int row0 = blockIdx.x * ROWS + rt * 4;
    int c0 = cg * 8;

    float4 accL[4] = {};
    float4 accH[4] = {};
    int rclamp[4];
#pragma unroll
    for (int r = 0; r < 4; ++r) rclamp[r] = min(row0 + r, nN - 1);

    if (BF16IN) {
        const unsigned* inu = (const unsigned*)in;
#pragma unroll 2
        for (int k8 = 0; k8 < KP / 8; ++k8) {
            uint4 a4[4];
#pragma unroll
            for (int r = 0; r < 4; ++r)
                a4[r] = *(const uint4*)(inu + (size_t)rclamp[r] * (KP / 2) + k8 * 4);
#pragma unroll
            for (int kk = 0; kk < 8; ++kk) {
                int k = k8 * 8 + kk;
                float4 wlo = *(const float4*)&Wl[k * NO + c0];
                float4 whi = *(const float4*)&Wl[k * NO + c0 + 4];
#pragma unroll
                for (int r = 0; r < 4; ++r) {
                    unsigned wd = ((const unsigned*)&a4[r])[kk >> 1];
                    float ar = (kk & 1) ? bfhi(wd) : bflo(wd);
                    accL[r].x += ar * wlo.x; accL[r].y += ar * wlo.y;
                    accL[r].z += ar * wlo.z; accL[r].w += ar * wlo.w;
                    accH[r].x += ar * whi.x; accH[r].y += ar * whi.y;
                    accH[r].z += ar * whi.z; accH[r].w += ar * whi.w;
                }
            }
        }
    } else {
        const float* inf = (const float*)in;
#pragma unroll 2
        for (int k4 = 0; k4 < KP / 4; ++k4) {
            float4 a[4];
#pragma unroll
            for (int r = 0; r < 4; ++r)
                a[r] = *(const float4*)(inf + (size_t)rclamp[r] * KP + k4 * 4);
#pragma unroll
            for (int kk = 0; kk < 4; ++kk) {
                int k = k4 * 4 + kk;
                float4 wlo = *(const float4*)&Wl[k * NO + c0];
                float4 whi = *(const float4*)&Wl[k * NO + c0 + 4];
#pragma unroll
                for (int r = 0; r < 4; ++r) {
                    float ar = (kk == 0) ? a[r].x : (kk == 1) ? a[r].y : (kk == 2) ? a[r].z : a[r].w;
                    accL[r].x += ar * wlo.x; accL[r].y += ar * wlo.y;
                    accL[r].z += ar * wlo.z; accL[r].w += ar * wlo.w;
                    accH[r].x += ar * whi.x; accH[r].y += ar * whi.y;
                    accH[r].z += ar * whi.z; accH[r].w += ar * whi.w;
                }
            }
        }
    }

#pragma unroll
    for (int r = 0; r < 4; ++r) {
        int row = row0 + r;
        if (row < nN) {
            float4 lo = accL[r], hi = accH[r];
            if (SCALE) {
                float sc = rowscale[row];
                lo.x *= sc; lo.y *= sc; lo.z *= sc; lo.w *= sc;
                hi.x *= sc; hi.y *= sc; hi.z *= sc; hi.w *= sc;
            }
            if (RELU) {
                lo.x = fmaxf(lo.x, 0.f); lo.y = fmaxf(lo.y, 0.f);
                lo.z = fmaxf(lo.z, 0.f); lo.w = fmaxf(lo.w, 0.f);
                hi.x = fmaxf(hi.x, 0.f); hi.y = fmaxf(hi.y, 0.f);
                hi.z = fmaxf(hi.z, 0.f); hi.w = fmaxf(hi.w, 0.f);
            }
            if (BF16OUT) {
                unsigned* ob = (unsigned*)out;
                uint4 p;
                p.x = bf16pair(lo.x, lo.y); p.y = bf16pair(lo.z, lo.w);
                p.z = bf16pair(hi.x, hi.y); p.w = bf16pair(hi.z, hi.w);
                *(uint4*)(ob + (size_t)row * (NO / 2) + c0 / 2) = p;
            } else {
                float* of = (float*)out;
                *(float4*)(of + (size_t)row * NO + c0) = lo;
                *(float4*)(of + (size_t)row * NO + c0 + 4) = hi;
            }
        }
    }
}

// ---------------- fused ReLU + per-graph max readout (32 nodes/wave) ----------------
__global__ void readout_kernel(const float* __restrict__ agg2, const int* __restrict__ gid,
                               unsigned* __restrict__ out, int nN) {
    const int NPW = 32;
    int wave = (int)(((unsigned)blockIdx.x * blockDim.x + threadIdx.x) >> 6);
    int lane = threadIdx.x & 63;
    int n0 = wave * NPW;
    if (n0 >= nN) return;
    int curg = gid[n0];
    float best = 0.0f;
    for (int i = 0; i < NPW; ++i) {
        int n = n0 + i;
        if (n >= nN) break;
        int g = gid[n];
        float v = fmaxf(agg2[(size_t)n * 64 + lane], 0.0f);
        if (g != curg) {
            atomicMax(&out[curg * 64 + lane], __float_as_uint(best));
            curg = g;
            best = v;
        } else {
            best = fmaxf(best, v);
        }
    }
    atomicMax(&out[curg * 64 + lane], __float_as_uint(best));
}

extern "C" void kernel_launch(void* const* d_in, const int* in_sizes, int n_in,
                              void* d_out, int out_size, void* d_ws, size_t ws_size,
                              hipStream_t stream) {
    const float* x   = (const float*)d_in[0];   // [100000, 69]
    const float* W1  = (const float*)d_in[1];   // [69, 128]
    const float* W2  = (const float*)d_in[2];   // [128, 64]
    const int*   src = (const int*)d_in[3];     // [1600000]
    const int*   dst = (const int*)d_in[4];     // [1600000]
    const int*   gid = (const int*)d_in[5];     // [100000] sorted

    char* w = (char*)d_ws;
    float* isqo    = (float*)w;                 w += N_NODES * 4;
    float* isqi    = (float*)w;                 w += N_NODES * 4;
    int* row_start = (int*)w;                   w += N_NODES * 4;
    int* ecol      = (int*)w;                   w += (size_t)N_EDGES * 4;
    int* cnt       = (int*)w;                   w += (size_t)NSCAN * 4;   // 392 KB
    int* blksum    = (int*)w;                   w += 1024 * 4;
    char* bufA     = w;                         w += (size_t)N_NODES * 72 * 4;  // h1 bf16 [N,64u32] -> agg2 f32 [N,64]
    char* bufB     = w;                         // time-shared region:
    unsigned* pdst       = (unsigned*)bufB;                                    // [nE] u32, dead after phase_d
    unsigned* xsu        = (unsigned*)bufB;                                    // [N,36] u32 bf16(x*isqo), prescale..gather1
    unsigned short* psrc = (unsigned short*)(bufB + (size_t)N_NODES * 36 * 4); // [nE] u16, dead after phase_d
    unsigned* h1         = (unsigned*)bufA;                                    // [N,64] u32 (bf16 h1), gather1..gemm2
    unsigned* y2s        = (unsigned*)bufB;                                    // [N,32] u32 (bf16 y2), gemm2..gather2
    float* agg2          = (float*)bufA;                                       // [N,64] f32, gather2..readout

    hipMemsetAsync(d_out, 0, (size_t)out_size * sizeof(float), stream);

    // ----- two-level CSR build, no global atomics -----
    part_hist<<<NBLKP, 256, 0, stream>>>(src, dst, cnt);
    scan1<<<NBSC, 256, 0, stream>>>(cnt, cnt, blksum, NSCAN);
    scan2<<<1, 256, 0, stream>>>(blksum, NBSC);
    part_scatter<<<NBLKP, 256, 0, stream>>>(src, dst, cnt, blksum, pdst, psrc);
    phase_d<<<2 * NBUCK, 1024, 0, stream>>>(pdst, psrc, cnt, blksum, ecol, row_start,
                                            isqi, isqo, N_NODES);
    prescale_kernel<<<(N_NODES * 64 + 255) / 256, 256, 0, stream>>>(x, isqo, xsu, N_NODES);

    // ----- layer 1: fused gather + GEMM1(+relu) -> bf16 h1 -----
    gather1_gemm1<<<(N_NODES + 15) / 16, 1024, 0, stream>>>(
        xsu, ecol, row_start, isqi, W1, h1, N_NODES, N_EDGES);

    // ----- layer 2: GEMM(bf16 in, *isqo -> bf16) -> gather(bf16 64) -----
    node_gemm<128, 128, 64, false, true, true, true><<<(N_NODES + 127) / 128, 256, 0, stream>>>(
        (const void*)h1, W2, isqo, (void*)y2s, N_NODES);
    gather2_kernel<<<(N_NODES * 64 + 255) / 256, 256, 0, stream>>>(
        y2s, ecol, row_start, isqi, agg2, N_NODES, N_EDGES);

    // ----- fused ReLU + per-graph max readout -----
    readout_kernel<<<((N_NODES + 31) / 32 * 64 + 255) / 256, 256, 0, stream>>>(
        agg2, gid, (unsigned*)d_out, N_NODES);
}

// Round 11
// 264.266 us; speedup vs baseline: 1.3360x; 1.3360x over previous
//
#include <hip/hip_runtime.h>

#define N_NODES 100000
#define N_EDGES 1600000
#define NUM_GRAPHS 128

#define BSH 10
#define NBUCK 98                  // ceil(N_NODES / 1024)
#define NBLKP 500                 // partition blocks
#define EPB (N_EDGES / NBLKP)     // 3200
#define SOFF (NBUCK * NBLKP)      // 49000
#define NSCAN (2 * NBUCK * NBLKP) // 98000
#define SCAN_BS 1024
#define NBSC ((NSCAN + SCAN_BS - 1) / SCAN_BS)  // 96

__device__ __forceinline__ unsigned bf16pair(float a, float b) {
    unsigned ua = __float_as_uint(a), ub = __float_as_uint(b);
    ua = (ua + 0x7FFFu + ((ua >> 16) & 1u)) >> 16;
    ub = (ub + 0x7FFFu + ((ub >> 16) & 1u)) >> 16;
    return ua | (ub << 16);
}
__device__ __forceinline__ float bflo(unsigned u) { return __uint_as_float(u << 16); }
__device__ __forceinline__ float bfhi(unsigned u) { return __uint_as_float(u & 0xFFFF0000u); }

// ---------------- Phase A: per-block coarse histograms (dst & src), wave-private sub-hists ----------------
__global__ __launch_bounds__(256) void part_hist(const int* __restrict__ src,
                                                 const int* __restrict__ dst,
                                                 int* __restrict__ cnt) {
    __shared__ int hd[4 * NBUCK], hs[4 * NBUCK];
    int t = threadIdx.x;
    for (int i = t; i < 4 * NBUCK; i += 256) { hd[i] = 0; hs[i] = 0; }
    __syncthreads();
    int wid = t >> 6;
    int* hdw = hd + wid * NBUCK;
    int* hsw = hs + wid * NBUCK;
    int e0 = blockIdx.x * EPB;
    for (int j = 4 * t; j + 3 < EPB; j += 1024) {
        int4 s4 = *(const int4*)(src + e0 + j);
        int4 d4 = *(const int4*)(dst + e0 + j);
        atomicAdd(&hdw[d4.x >> BSH], 1); atomicAdd(&hdw[d4.y >> BSH], 1);
        atomicAdd(&hdw[d4.z >> BSH], 1); atomicAdd(&hdw[d4.w >> BSH], 1);
        atomicAdd(&hsw[s4.x >> BSH], 1); atomicAdd(&hsw[s4.y >> BSH], 1);
        atomicAdd(&hsw[s4.z >> BSH], 1); atomicAdd(&hsw[s4.w >> BSH], 1);
    }
    __syncthreads();
    int bk = blockIdx.x;
    for (int i = t; i < NBUCK; i += 256) {
        cnt[i * NBLKP + bk] = hd[i] + hd[NBUCK + i] + hd[2 * NBUCK + i] + hd[3 * NBUCK + i];
        cnt[SOFF + i * NBLKP + bk] = hs[i] + hs[NBUCK + i] + hs[2 * NBUCK + i] + hs[3 * NBUCK + i];
    }
}

// ---------------- exclusive scan ----------------
__global__ __launch_bounds__(256) void scan1(const int* __restrict__ cnt, int* __restrict__ excl,
                                             int* __restrict__ blksum, int n) {
    __shared__ int tmp[256];
    int t = threadIdx.x;
    int idx0 = blockIdx.x * SCAN_BS + t * 4;
    int v[4];
#pragma unroll
    for (int k = 0; k < 4; ++k) { int i = idx0 + k; v[k] = (i < n) ? cnt[i] : 0; }
    int sum = v[0] + v[1] + v[2] + v[3];
    tmp[t] = sum;
    __syncthreads();
    for (int off = 1; off < 256; off <<= 1) {
        int y = (t >= off) ? tmp[t - off] : 0;
        __syncthreads();
        tmp[t] += y;
        __syncthreads();
    }
    int run = (t > 0) ? tmp[t - 1] : 0;
#pragma unroll
    for (int k = 0; k < 4; ++k) { int i = idx0 + k; if (i < n) excl[i] = run; run += v[k]; }
    if (t == 255) blksum[blockIdx.x] = tmp[255];
}

__global__ __launch_bounds__(256) void scan2(int* __restrict__ blksum, int nb) {
    __shared__ int tmp[256];
    int t = threadIdx.x;
    int C = (nb + 255) / 256;
    int base = t * C;
    int s = 0;
    for (int k = 0; k < C; ++k) { int i = base + k; if (i < nb) s += blksum[i]; }
    tmp[t] = s;
    __syncthreads();
    for (int off = 1; off < 256; off <<= 1) {
        int y = (t >= off) ? tmp[t - off] : 0;
        __syncthreads();
        tmp[t] += y;
        __syncthreads();
    }
    int run = (t > 0) ? tmp[t - 1] : 0;
    for (int k = 0; k < C; ++k) {
        int i = base + k;
        if (i < nb) { int v = blksum[i]; blksum[i] = run; run += v; }
    }
}

// ---------------- Phase C: partition edges into coarse buckets (LDS cursors) ----------------
__global__ __launch_bounds__(256) void part_scatter(const int* __restrict__ src,
                                                    const int* __restrict__ dst,
                                                    const int* __restrict__ cnt,
                                                    const int* __restrict__ blk,
                                                    unsigned* __restrict__ pdst,
                                                    unsigned short* __restrict__ psrc) {
    __shared__ int cd[NBUCK], cs[NBUCK];
    int bk = blockIdx.x;
    int t = threadIdx.x;
    for (int i = t; i < NBUCK; i += 256) {
        int ii = i * NBLKP + bk;
        cd[i] = cnt[ii] + blk[ii >> 10];
        int jj = SOFF + i * NBLKP + bk;
        cs[i] = cnt[jj] + blk[jj >> 10] - N_EDGES;
    }
    __syncthreads();
    int e0 = bk * EPB;
    for (int j = 4 * t; j + 3 < EPB; j += 1024) {
        int4 s4 = *(const int4*)(src + e0 + j);
        int4 d4 = *(const int4*)(dst + e0 + j);
        int ss[4] = { s4.x, s4.y, s4.z, s4.w };
        int dd[4] = { d4.x, d4.y, d4.z, d4.w };
#pragma unroll
        for (int u = 0; u < 4; ++u) {
            int s = ss[u], d = dd[u];
            int pd = atomicAdd(&cd[d >> BSH], 1);
            pdst[pd] = (unsigned)s | ((unsigned)(d & 1023) << 17);
            int ps = atomicAdd(&cs[s >> BSH], 1);
            psrc[ps] = (unsigned short)(s & 1023);
        }
    }
}

// ---------------- Phase D (merged): blocks 0..NBUCK-1 build CSR; blocks NBUCK.. src degrees + prescale ----------------
__global__ __launch_bounds__(1024) void phase_d(const unsigned* __restrict__ pdst,
                                                const unsigned short* __restrict__ psrc,
                                                const int* __restrict__ cnt,
                                                const int* __restrict__ blk,
                                                int* __restrict__ ecol, int* __restrict__ row_start,
                                                float* __restrict__ isqi, float* __restrict__ isqo,
                                                const float* __restrict__ x,
                                                unsigned* __restrict__ xsu,
                                                int nN) {
    __shared__ int lh[1024];
    __shared__ int lsc[1024];
    __shared__ float scs[1024];
    int t = threadIdx.x;
    if (blockIdx.x < NBUCK) {
        int bu = blockIdx.x;
        int i0 = bu * NBLKP;
        int b0 = cnt[i0] + blk[i0 >> 10];
        int b1;
        if (bu == NBUCK - 1) b1 = N_EDGES;
        else { int i1 = i0 + NBLKP; b1 = cnt[i1] + blk[i1 >> 10]; }
        lh[t] = 0;
        __syncthreads();
        for (int j = b0 + t; j < b1; j += 1024)
            atomicAdd(&lh[pdst[j] >> 17], 1);
        __syncthreads();
        int myc = lh[t];
        lsc[t] = myc;
        __syncthreads();
        for (int off = 1; off < 1024; off <<= 1) {
            int y = (t >= off) ? lsc[t - off] : 0;
            __syncthreads();
            lsc[t] += y;
            __syncthreads();
        }
        int excl = lsc[t] - myc;
        int node = (bu << BSH) + t;
        if (node < nN) {
            row_start[node] = b0 + excl;
            isqi[node] = rsqrtf(fmaxf((float)myc, 1.0f));
        }
        __syncthreads();
        lh[t] = b0 + excl;   // reuse as cursor
        __syncthreads();
        for (int j = b0 + t; j < b1; j += 1024) {
            unsigned w = pdst[j];
            int pos = atomicAdd(&lh[w >> 17], 1);
            ecol[pos] = (int)(w & 0x1FFFFu);
        }
    } else {
        int bu = blockIdx.x - NBUCK;
        int i0 = SOFF + bu * NBLKP;
        int b0 = cnt[i0] + blk[i0 >> 10] - N_EDGES;
        int b1;
        if (bu == NBUCK - 1) b1 = N_EDGES;
        else { int i1 = i0 + NBLKP; b1 = cnt[i1] + blk[i1 >> 10] - N_EDGES; }
        lh[t] = 0;
        __syncthreads();
        for (int j = b0 + t; j < b1; j += 1024)
            atomicAdd(&lh[psrc[j]], 1);
        __syncthreads();
        int n0 = bu << BSH;
        float v = rsqrtf(fmaxf((float)lh[t], 1.0f));
        scs[t] = v;
        int node = n0 + t;
        if (node < nN) isqo[node] = v;
        __syncthreads();
        // fused prescale: xsu = bf16(x * isqo) for this bucket's nodes
        int rows = min(1024, nN - n0);
        if (rows <= 0) return;
        for (int idx = t; idx < rows * 36; idx += 1024) {
            int r = idx / 36, c2 = idx - r * 36;
            float s = scs[r];
            int c = 2 * c2;
            float a = (c < 69) ? x[(size_t)(n0 + r) * 69 + c] * s : 0.0f;
            float b = (c + 1 < 69) ? x[(size_t)(n0 + r) * 69 + c + 1] * s : 0.0f;
            xsu[(size_t)(n0 + r) * 36 + c2] = bf16pair(a, b);
        }
    }
}

// ---------------- gather1: agg[n][0..71] (f32) = dscale[n] * sum feat_bf16[src]; lanes 0..35 ----------------
__global__ void gather1_kernel(const unsigned* __restrict__ feat, const int* __restrict__ ecol,
                               const int* __restrict__ row_start, const float* __restrict__ dscale,
                               float* __restrict__ agg, int nN, int nE) {
    int wave = (int)(((unsigned)blockIdx.x * blockDim.x + threadIdx.x) >> 6);
    int lane = threadIdx.x & 63;
    if (wave >= nN) return;
    int beg = row_start[wave];
    int end = (wave == nN - 1) ? nE : row_start[wave + 1];
    bool act = (lane < 36);
    float ax = 0.0f, ay = 0.0f;
    for (int j0 = beg; j0 < end; j0 += 64) {
        int ne = min(64, end - j0);
        int eidx = (lane < ne) ? ecol[j0 + lane] : 0;
        int k = 0;
        for (; k + 8 <= ne; k += 8) {
            unsigned v[8];
#pragma unroll
            for (int u = 0; u < 8; ++u) {
                int s = __shfl(eidx, k + u);
                v[u] = act ? feat[(size_t)s * 36 + lane] : 0u;
            }
#pragma unroll
            for (int u = 0; u < 8; ++u) { ax += bflo(v[u]); ay += bfhi(v[u]); }
        }
        for (; k + 2 <= ne; k += 2) {
            int s0 = __shfl(eidx, k), s1 = __shfl(eidx, k + 1);
            unsigned v0 = act ? feat[(size_t)s0 * 36 + lane] : 0u;
            unsigned v1 = act ? feat[(size_t)s1 * 36 + lane] : 0u;
            ax += bflo(v0) + bflo(v1); ay += bfhi(v0) + bfhi(v1);
        }
        for (; k < ne; ++k) {
            int s = __shfl(eidx, k);
            unsigned v = act ? feat[(size_t)s * 36 + lane] : 0u;
            ax += bflo(v); ay += bfhi(v);
        }
    }
    if (act) {
        float dsc = dscale[wave];
        ((float2*)(agg + (size_t)wave * 72))[lane] = make_float2(ax * dsc, ay * dsc);
    }
}

// ---------------- gather2: agg[n][0..63] f32; 2 edges/step ----------------
__global__ void gather2_kernel(const unsigned* __restrict__ feat, const int* __restrict__ ecol,
                               const int* __restrict__ row_start, const float* __restrict__ dscale,
                               float* __restrict__ agg, int nN, int nE) {
    int wave = (int)(((unsigned)blockIdx.x * blockDim.x + threadIdx.x) >> 6);
    int lane = threadIdx.x & 63;
    if (wave >= nN) return;
    int beg = row_start[wave];
    int end = (wave == nN - 1) ? nE : row_start[wave + 1];
    int half = lane >> 5;
    int c = lane & 31;
    float ax = 0.0f, ay = 0.0f;
    for (int j0 = beg; j0 < end; j0 += 64) {
        int ne = min(64, end - j0);
        int eidx = (lane < ne) ? ecol[j0 + lane] : 0;
        int k = 0;
        for (; k + 16 <= ne; k += 16) {
            unsigned v[8];
#pragma unroll
            for (int u = 0; u < 8; ++u) {
                int s = __shfl(eidx, k + 2 * u + half);
                v[u] = feat[(size_t)s * 32 + c];
            }
#pragma unroll
            for (int u = 0; u < 8; ++u) { ax += bflo(v[u]); ay += bfhi(v[u]); }
        }
        for (; k + 2 <= ne; k += 2) {
            int s = __shfl(eidx, k + half);
            unsigned v = feat[(size_t)s * 32 + c];
            ax += bflo(v); ay += bfhi(v);
        }
        if (k < ne) {
            int s = __shfl(eidx, k);
            if (half == 0) {
                unsigned v = feat[(size_t)s * 32 + c];
                ax += bflo(v); ay += bfhi(v);
            }
        }
    }
    ax += __shfl_xor(ax, 32);
    ay += __shfl_xor(ay, 32);
    if (half == 0) {
        float dsc = dscale[wave];
        ((float2*)(agg + (size_t)wave * 64))[c] = make_float2(ax * dsc, ay * dsc);
    }
}

// ---------------- register-blocked node GEMM (A f32 or packed bf16; out f32 or packed bf16) ----------------
template<int KP, int K, int NO, bool RELU, bool SCALE, bool BF16OUT, bool BF16IN>
__global__ __launch_bounds__(256) void node_gemm(const void* __restrict__ in,
                                                 const float* __restrict__ W,
                                                 const float* __restrict__ rowscale,
                                                 void* __restrict__ out, int nN) {
    constexpr int CG = NO / 8;
    constexpr int RT = 256 / CG;
    constexpr int ROWS = RT * 4;
    __shared__ float Wl[KP * NO];
    for (int i = threadIdx.x; i < KP * NO; i += 256)
        Wl[i] = (i < K * NO) ? W[i] : 0.0f;
    __syncthreads();

    int cg = threadIdx.x % CG;
    int rt = threadIdx.x / CG;
    int row0 = blockIdx.x * ROWS + rt * 4;
    int c0 = cg * 8;

    float4 accL[4] = {};
    float4 accH[4] = {};
    int rclamp[4];
#pragma unroll
    for (int r = 0; r < 4; ++r) rclamp[r] = min(row0 + r, nN - 1);

    if (BF16IN) {
        const unsigned* inu = (const unsigned*)in;
#pragma unroll 2
        for (int k8 = 0; k8 < KP / 8; ++k8) {
            uint4 a4[4];
#pragma unroll
            for (int r = 0; r < 4; ++r)
                a4[r] = *(const uint4*)(inu + (size_t)rclamp[r] * (KP / 2) + k8 * 4);
#pragma unroll
            for (int kk = 0; kk < 8; ++kk) {
                int k = k8 * 8 + kk;
                float4 wlo = *(const float4*)&Wl[k * NO + c0];
                float4 whi = *(const float4*)&Wl[k * NO + c0 + 4];
#pragma unroll
                for (int r = 0; r < 4; ++r) {
                    unsigned wd = ((const unsigned*)&a4[r])[kk >> 1];
                    float ar = (kk & 1) ? bfhi(wd) : bflo(wd);
                    accL[r].x += ar * wlo.x; accL[r].y += ar * wlo.y;
                    accL[r].z += ar * wlo.z; accL[r].w += ar * wlo.w;
                    accH[r].x += ar * whi.x; accH[r].y += ar * whi.y;
                    accH[r].z += ar * whi.z; accH[r].w += ar * whi.w;
                }
            }
        }
    } else {
        const float* inf = (const float*)in;
#pragma unroll 2
        for (int k4 = 0; k4 < KP / 4; ++k4) {
            float4 a[4];
#pragma unroll
            for (int r = 0; r < 4; ++r)
                a[r] = *(const float4*)(inf + (size_t)rclamp[r] * KP + k4 * 4);
#pragma unroll
            for (int kk = 0; kk < 4; ++kk) {
                int k = k4 * 4 + kk;
                float4 wlo = *(const float4*)&Wl[k * NO + c0];
                float4 whi = *(const float4*)&Wl[k * NO + c0 + 4];
#pragma unroll
                for (int r = 0; r < 4; ++r) {
                    float ar = (kk == 0) ? a[r].x : (kk == 1) ? a[r].y : (kk == 2) ? a[r].z : a[r].w;
                    accL[r].x += ar * wlo.x; accL[r].y += ar * wlo.y;
                    accL[r].z += ar * wlo.z; accL[r].w += ar * wlo.w;
                    accH[r].x += ar * whi.x; accH[r].y += ar * whi.y;
                    accH[r].z += ar * whi.z; accH[r].w += ar * whi.w;
                }
            }
        }
    }

#pragma unroll
    for (int r = 0; r < 4; ++r) {
        int row = row0 + r;
        if (row < nN) {
            float4 lo = accL[r], hi = accH[r];
            if (SCALE) {
                float sc = rowscale[row];
                lo.x *= sc; lo.y *= sc; lo.z *= sc; lo.w *= sc;
                hi.x *= sc; hi.y *= sc; hi.z *= sc; hi.w *= sc;
            }
            if (RELU) {
                lo.x = fmaxf(lo.x, 0.f); lo.y = fmaxf(lo.y, 0.f);
                lo.z = fmaxf(lo.z, 0.f); lo.w = fmaxf(lo.w, 0.f);
                hi.x = fmaxf(hi.x, 0.f); hi.y = fmaxf(hi.y, 0.f);
                hi.z = fmaxf(hi.z, 0.f); hi.w = fmaxf(hi.w, 0.f);
            }
            if (BF16OUT) {
                unsigned* ob = (unsigned*)out;
                uint4 p;
                p.x = bf16pair(lo.x, lo.y); p.y = bf16pair(lo.z, lo.w);
                p.z = bf16pair(hi.x, hi.y); p.w = bf16pair(hi.z, hi.w);
                *(uint4*)(ob + (size_t)row * (NO / 2) + c0 / 2) = p;
            } else {
                float* of = (float*)out;
                *(float4*)(of + (size_t)row * NO + c0) = lo;
                *(float4*)(of + (size_t)row * NO + c0 + 4) = hi;
            }
        }
    }
}

// ---------------- fused ReLU + per-graph max readout (32 nodes/wave) ----------------
__global__ void readout_kernel(const float* __restrict__ agg2, const int* __restrict__ gid,
                               unsigned* __restrict__ out, int nN) {
    const int NPW = 32;
    int wave = (int)(((unsigned)blockIdx.x * blockDim.x + threadIdx.x) >> 6);
    int lane = threadIdx.x & 63;
    int n0 = wave * NPW;
    if (n0 >= nN) return;
    int curg = gid[n0];
    float best = 0.0f;
    for (int i = 0; i < NPW; ++i) {
        int n = n0 + i;
        if (n >= nN) break;
        int g = gid[n];
        float v = fmaxf(agg2[(size_t)n * 64 + lane], 0.0f);
        if (g != curg) {
            atomicMax(&out[curg * 64 + lane], __float_as_uint(best));
            curg = g;
            best = v;
        } else {
            best = fmaxf(best, v);
        }
    }
    atomicMax(&out[curg * 64 + lane], __float_as_uint(best));
}

extern "C" void kernel_launch(void* const* d_in, const int* in_sizes, int n_in,
                              void* d_out, int out_size, void* d_ws, size_t ws_size,
                              hipStream_t stream) {
    const float* x   = (const float*)d_in[0];   // [100000, 69]
    const float* W1  = (const float*)d_in[1];   // [69, 128]
    const float* W2  = (const float*)d_in[2];   // [128, 64]
    const int*   src = (const int*)d_in[3];     // [1600000]
    const int*   dst = (const int*)d_in[4];     // [1600000]
    const int*   gid = (const int*)d_in[5];     // [100000] sorted

    char* w = (char*)d_ws;
    float* isqo    = (float*)w;                 w += N_NODES * 4;
    float* isqi    = (float*)w;                 w += N_NODES * 4;
    int* row_start = (int*)w;                   w += N_NODES * 4;
    int* ecol      = (int*)w;                   w += (size_t)N_EDGES * 4;
    int* cnt       = (int*)w;                   w += (size_t)NSCAN * 4;   // 392 KB
    int* blksum    = (int*)w;                   w += 1024 * 4;
    float* bufA    = (float*)w;                 w += (size_t)N_NODES * 72 * 4;  // agg1 f32 [N,72] -> y2s bf16 [N,32u32]
    char* bufB     = w;                         // time-shared region, 25.6 MB:
    // layout during CSR build (phase_d runs CSR-read(pdst,psrc) and xsu-write CONCURRENTLY -> disjoint):
    unsigned* pdst       = (unsigned*)bufB;                                     // [nE] u32  @ 0..6.4MB
    unsigned short* psrc = (unsigned short*)(bufB + (size_t)N_EDGES * 4);       // [nE] u16  @ 6.4..9.6MB
    unsigned* xsu        = (unsigned*)(bufB + (size_t)N_EDGES * 6);             // [N,36]u32 @ 9.6..24MB
    unsigned* h1         = (unsigned*)bufB;                                     // [N,64] u32 (bf16 h1), gemm1..gemm2
    unsigned* y2s        = (unsigned*)bufA;                                     // [N,32] u32 (bf16 y2), gemm2..gather2
    float* agg2          = (float*)bufB;                                        // [N,64] f32, gather2..readout

    hipMemsetAsync(d_out, 0, (size_t)out_size * sizeof(float), stream);

    // ----- two-level CSR build, no global atomics -----
    part_hist<<<NBLKP, 256, 0, stream>>>(src, dst, cnt);
    scan1<<<NBSC, 256, 0, stream>>>(cnt, cnt, blksum, NSCAN);
    scan2<<<1, 256, 0, stream>>>(blksum, NBSC);
    part_scatter<<<NBLKP, 256, 0, stream>>>(src, dst, cnt, blksum, pdst, psrc);
    phase_d<<<2 * NBUCK, 1024, 0, stream>>>(pdst, psrc, cnt, blksum, ecol, row_start,
                                            isqi, isqo, x, xsu, N_NODES);

    // ----- layer 1: gather(bf16 [N,36]) -> GEMM(+relu -> bf16 h1) -----
    gather1_kernel<<<(N_NODES * 64 + 255) / 256, 256, 0, stream>>>(
        xsu, ecol, row_start, isqi, bufA, N_NODES, N_EDGES);
    node_gemm<72, 69, 128, true, false, true, false><<<(N_NODES + 63) / 64, 256, 0, stream>>>(
        (const void*)bufA, W1, nullptr, (void*)h1, N_NODES);

    // ----- layer 2: GEMM(bf16 in, *isqo -> bf16 y2s) -> gather(bf16 64) -----
    node_gemm<128, 128, 64, false, true, true, true><<<(N_NODES + 127) / 128, 256, 0, stream>>>(
        (const void*)h1, W2, isqo, (void*)y2s, N_NODES);
    gather2_kernel<<<(N_NODES * 64 + 255) / 256, 256, 0, stream>>>(
        y2s, ecol, row_start, isqi, agg2, N_NODES, N_EDGES);

    // ----- fused ReLU + per-graph max readout -----
    readout_kernel<<<((N_NODES + 31) / 32 * 64 + 255) / 256, 256, 0, stream>>>(
        agg2, gid, (unsigned*)d_out, N_NODES);
}